// Round 1
// 1882.095 us; speedup vs baseline: 1.3644x; 1.3644x over previous
//
#include <hip/hip_runtime.h>

// out[b,s,o] = sum_i x[b,s,i] * (w[o,i] * scale[o/128, i/128])
// M = B*S = 4096, N = OUT = 18432, K = IN = 7168.
// v2: 256x256 8-phase GEMM (T1 XCD swizzle + T2 LDS XOR swizzle + T3/T4
// counted-vmcnt deep pipeline + T5 setprio), per the verified m201 template.

#define M_DIM 4096
#define N_DIM 18432
#define K_DIM 7168
#define SCALE_COLS 56          // K/128
#define NK (K_DIM / 64)        // 112 K-tiles (BK = 64)
#define NBLK ((M_DIM / 256) * (N_DIM / 256))   // 16 * 72 = 1152

typedef unsigned short u16;
typedef short short8 __attribute__((ext_vector_type(8)));
typedef float floatx4 __attribute__((ext_vector_type(4)));
typedef unsigned short ushortx8 __attribute__((ext_vector_type(8)));
typedef float float4v __attribute__((ext_vector_type(4)));

typedef __attribute__((address_space(1))) unsigned int glb_uint;
typedef __attribute__((address_space(3))) unsigned int lds_uint;

__device__ __forceinline__ void async_copy16(const void* g, void* l) {
    __builtin_amdgcn_global_load_lds((glb_uint*)(g), (lds_uint*)(l), 16, 0, 0);
}

#define BARRIER() asm volatile("s_barrier" ::: "memory")

__device__ __forceinline__ u16 f32_to_bf16_rne(float f) {
    union { float f; unsigned int u; } v; v.f = f;
    unsigned int u = v.u;
    u += 0x7fffu + ((u >> 16) & 1u);
    return (u16)(u >> 16);
}

// ---------------------------------------------------------------------------
// x (fp32) -> bf16, 8 elements per thread.
__global__ __launch_bounds__(256) void cvt_x_kernel(
    const float* __restrict__ x, ushortx8* __restrict__ xb)
{
    size_t idx = (size_t)blockIdx.x * 256 + threadIdx.x;
    const float4v* px = (const float4v*)(x) + idx * 2;
    float4v f0 = px[0], f1 = px[1];
    ushortx8 r;
    r[0] = f32_to_bf16_rne(f0[0]); r[1] = f32_to_bf16_rne(f0[1]);
    r[2] = f32_to_bf16_rne(f0[2]); r[3] = f32_to_bf16_rne(f0[3]);
    r[4] = f32_to_bf16_rne(f1[0]); r[5] = f32_to_bf16_rne(f1[1]);
    r[6] = f32_to_bf16_rne(f1[2]); r[7] = f32_to_bf16_rne(f1[3]);
    xb[idx] = r;
}

// ---------------------------------------------------------------------------
// w (fp32) * scale -> bf16, 8 elements (along i) per thread.
__global__ __launch_bounds__(256) void dequant_w_kernel(
    const float* __restrict__ w, const float* __restrict__ scale,
    ushortx8* __restrict__ wb)
{
    size_t idx = (size_t)blockIdx.x * 256 + threadIdx.x;
    int i8 = (int)(idx % (K_DIM / 8));
    int o  = (int)(idx / (K_DIM / 8));
    float s = scale[(o >> 7) * SCALE_COLS + (i8 >> 4)];
    const float4v* pw = (const float4v*)(w) + idx * 2;
    float4v f0 = pw[0], f1 = pw[1];
    ushortx8 r;
    r[0] = f32_to_bf16_rne(f0[0] * s); r[1] = f32_to_bf16_rne(f0[1] * s);
    r[2] = f32_to_bf16_rne(f0[2] * s); r[3] = f32_to_bf16_rne(f0[3] * s);
    r[4] = f32_to_bf16_rne(f1[0] * s); r[5] = f32_to_bf16_rne(f1[1] * s);
    r[6] = f32_to_bf16_rne(f1[2] * s); r[7] = f32_to_bf16_rne(f1[3] * s);
    wb[idx] = r;
}

// ---------------------------------------------------------------------------
// 256x256 8-phase bf16 GEMM.  C[m][n] = sum_k A[m][k] * Bt[n][k].
// 512 threads = 8 waves (2 m x 4 n), each wave owns a 128x64 output tile
// = acc[8][4] of 16x16 fragments.  BK=64 (2 MFMA K-halves per fragment).
// LDS: 2 buffers x (A 256x64 + B 256x64) bf16 = 128 KiB.
//
// Pipeline (per K-tile t, buf = t&1; "phase" = {ds_read / stage / barrier /
// MFMA / barrier}; 4 phases per K-tile = 8 per 2-tile iteration):
//   P1: ds_read A m0-3 + B n0-1;          MFMA q0 (m0-3 x n0-1)
//   P2: ds_read B n2-3;                   MFMA q1 (m0-3 x n2-3)
//   P3: ds_read A m4-7; stage B(t+2);     MFMA q2 (m4-7 x n0-1)
//   P4:                 stage A(t+2);     MFMA q3 (m4-7 x n2-3); vmcnt(8)
// Race safety: B reads complete before P2-end barrier -> stage B in P3 is
// safe; A reads complete before P3-end barrier -> stage A in P4 is safe.
// vmcnt(8) leaves tile t+2's 8 loads in flight, guarantees tile t+1 landed.
//
// T2 swizzle: LDS slot (16B units within a 128B row) = slot ^ (row & 7).
// Write side: global source column pre-swizzled (global_load_lds writes
// linearly); read side: ds_read applies the same XOR.  Lanes l15=0..15 of a
// quad then hit 8 distinct 16B slots (2-way = free) instead of 1 (16-way).

#define STAGE_OP(buf, op, gptr, kt) do {                                \
    const char* _g = (gptr) + (size_t)(kt) * 128;                       \
    char* _l = (char*)&lds[(buf)][(op)][0] + wave * 1024;               \
    async_copy16(_g,             _l);                                   \
    async_copy16(_g + rskip,     _l + 8192);                            \
    async_copy16(_g + 2 * rskip, _l + 16384);                           \
    async_copy16(_g + 3 * rskip, _l + 24576);                           \
} while (0)

__global__ __launch_bounds__(512, 2) void gemm_bf16_8ph(
    const u16* __restrict__ A, const u16* __restrict__ B,
    float* __restrict__ C)
{
    __shared__ u16 lds[2][2][256 * 64];   // [buf][0=A,1=B][row*64 + k]

    const int tid  = threadIdx.x;
    const int lane = tid & 63;
    const int wave = tid >> 6;
    const int quad = lane >> 4;
    const int l15  = lane & 15;
    const int wr   = wave >> 2;    // 0..1: rows wr*128..+128
    const int wc   = wave & 3;     // 0..3: cols wc*64..+64

    // XCD-bijective swizzle (1152 % 8 == 0), m-fastest within each chunk:
    // each XCD gets 9 consecutive n-panels x all 16 m-tiles (B panel 3.67 MB
    // fits its 4 MB L2; concurrent window A+B ~118 MB fits L3).
    int wg = (blockIdx.x & 7) * (NBLK / 8) + (blockIdx.x >> 3);
    const int m0 = (wg & 15) * 256;
    const int n0 = (wg >> 4) * 256;

    // Staging: 16 B/thread, 8 threads/row, 64 rows/instruction, 4 instr/op.
    const int srow  = tid >> 3;                        // 0..63
    const int scolb = ((tid & 7) ^ (srow & 7)) << 4;   // pre-swizzled col (B)
    const char* gA = (const char*)(A + (size_t)(m0 + srow) * K_DIM) + scolb;
    const char* gB = (const char*)(B + (size_t)(n0 + srow) * K_DIM) + scolb;
    const size_t rskip = (size_t)64 * K_DIM * 2;       // +64 rows, bytes

    // ds_read: row = (wave row) + frag*16 + l15; slot = (quad + 4*kk) ^ (l15&7)
    const int swz = l15 & 7;
    const int sl0 = ((quad    ) ^ swz) << 3;   // u16 offset, kk=0
    const int sl1 = ((quad + 4) ^ swz) << 3;   // u16 offset, kk=1
    const u16* pA0 = &lds[0][0][(wr * 128 + l15) * 64];
    const u16* pB0 = &lds[0][1][(wc * 64  + l15) * 64];

    floatx4 acc[8][4];
#pragma unroll
    for (int m = 0; m < 8; ++m)
#pragma unroll
        for (int n = 0; n < 4; ++n) acc[m][n] = (floatx4)0.0f;

    short8 af[4][2], bf[4][2];

    // Prologue: tiles 0 (buf0) and 1 (buf1); wait tile 0 (8 newest in flight).
    STAGE_OP(0, 0, gA, 0); STAGE_OP(0, 1, gB, 0);
    STAGE_OP(1, 0, gA, 1); STAGE_OP(1, 1, gB, 1);
    asm volatile("s_waitcnt vmcnt(8)" ::: "memory");
    BARRIER();

    for (int t = 0; t < NK; ++t) {
        const int buf = t & 1;
        const u16* pA = pA0 + buf * (2 * 16384);
        const u16* pB = pB0 + buf * (2 * 16384);

        // ---- P1 -------------------------------------------------------
#pragma unroll
        for (int m = 0; m < 4; ++m) {
            af[m][0] = *(const short8*)(pA + m * 1024 + sl0);
            af[m][1] = *(const short8*)(pA + m * 1024 + sl1);
        }
#pragma unroll
        for (int n = 0; n < 2; ++n) {
            bf[n][0] = *(const short8*)(pB + n * 1024 + sl0);
            bf[n][1] = *(const short8*)(pB + n * 1024 + sl1);
        }
        BARRIER();
        __builtin_amdgcn_s_setprio(1);
#pragma unroll
        for (int m = 0; m < 4; ++m)
#pragma unroll
            for (int n = 0; n < 2; ++n) {
                acc[m][n] = __builtin_amdgcn_mfma_f32_16x16x32_bf16(
                    af[m][0], bf[n][0], acc[m][n], 0, 0, 0);
                acc[m][n] = __builtin_amdgcn_mfma_f32_16x16x32_bf16(
                    af[m][1], bf[n][1], acc[m][n], 0, 0, 0);
            }
        __builtin_amdgcn_s_setprio(0);
        BARRIER();

        // ---- P2 -------------------------------------------------------
#pragma unroll
        for (int n = 2; n < 4; ++n) {
            bf[n][0] = *(const short8*)(pB + n * 1024 + sl0);
            bf[n][1] = *(const short8*)(pB + n * 1024 + sl1);
        }
        BARRIER();
        __builtin_amdgcn_s_setprio(1);
#pragma unroll
        for (int m = 0; m < 4; ++m)
#pragma unroll
            for (int n = 2; n < 4; ++n) {
                acc[m][n] = __builtin_amdgcn_mfma_f32_16x16x32_bf16(
                    af[m][0], bf[n][0], acc[m][n], 0, 0, 0);
                acc[m][n] = __builtin_amdgcn_mfma_f32_16x16x32_bf16(
                    af[m][1], bf[n][1], acc[m][n], 0, 0, 0);
            }
        __builtin_amdgcn_s_setprio(0);
        BARRIER();

        // ---- P3 -------------------------------------------------------
#pragma unroll
        for (int m = 0; m < 4; ++m) {
            af[m][0] = *(const short8*)(pA + (m + 4) * 1024 + sl0);
            af[m][1] = *(const short8*)(pA + (m + 4) * 1024 + sl1);
        }
        if (t + 2 < NK) { STAGE_OP(buf, 1, gB, t + 2); }
        BARRIER();
        __builtin_amdgcn_s_setprio(1);
#pragma unroll
        for (int m = 0; m < 4; ++m)
#pragma unroll
            for (int n = 0; n < 2; ++n) {
                acc[m + 4][n] = __builtin_amdgcn_mfma_f32_16x16x32_bf16(
                    af[m][0], bf[n][0], acc[m + 4][n], 0, 0, 0);
                acc[m + 4][n] = __builtin_amdgcn_mfma_f32_16x16x32_bf16(
                    af[m][1], bf[n][1], acc[m + 4][n], 0, 0, 0);
            }
        __builtin_amdgcn_s_setprio(0);
        BARRIER();

        // ---- P4 -------------------------------------------------------
        if (t + 2 < NK) { STAGE_OP(buf, 0, gA, t + 2); }
        BARRIER();
        __builtin_amdgcn_s_setprio(1);
#pragma unroll
        for (int m = 0; m < 4; ++m)
#pragma unroll
            for (int n = 2; n < 4; ++n) {
                acc[m + 4][n] = __builtin_amdgcn_mfma_f32_16x16x32_bf16(
                    af[m][0], bf[n][0], acc[m + 4][n], 0, 0, 0);
                acc[m + 4][n] = __builtin_amdgcn_mfma_f32_16x16x32_bf16(
                    af[m][1], bf[n][1], acc[m + 4][n], 0, 0, 0);
            }
        __builtin_amdgcn_s_setprio(0);
        if (t < NK - 2) { asm volatile("s_waitcnt vmcnt(8)" ::: "memory"); }
        else            { asm volatile("s_waitcnt vmcnt(0)" ::: "memory"); }
        BARRIER();
    }

    // Epilogue: C/D layout col = l15, row = quad*4 + i (verified v1 mapping).
#pragma unroll
    for (int m = 0; m < 8; ++m) {
#pragma unroll
        for (int n = 0; n < 4; ++n) {
            const int col = n0 + wc * 64 + n * 16 + l15;
            const size_t rbase = (size_t)(m0 + wr * 128 + m * 16 + quad * 4);
#pragma unroll
            for (int i = 0; i < 4; ++i)
                C[(rbase + i) * N_DIM + col] = acc[m][n][i];
        }
    }
}

// ---------------------------------------------------------------------------
// Fallback (if workspace too small): fp32 LDS-tiled GEMM w/ inline dequant.
__global__ __launch_bounds__(256) void fallback_gemm(
    const float* __restrict__ A, const float* __restrict__ Bw,
    const float* __restrict__ scale, float* __restrict__ C)
{
    __shared__ float sA[64][17];
    __shared__ float sB[64][17];
    const int tid = threadIdx.x;
    const int tx = tid & 15, ty = tid >> 4;
    const int n0 = blockIdx.x * 64;
    const int m0 = blockIdx.y * 64;
    const int lrow = tid >> 2;
    const int lk   = (tid & 3) * 4;
    float acc[4][4] = {};
    for (int k0 = 0; k0 < K_DIM; k0 += 16) {
        float4 a = *(const float4*)(A + (size_t)(m0 + lrow) * K_DIM + k0 + lk);
        float s = scale[((n0 + lrow) >> 7) * SCALE_COLS + ((k0 + lk) >> 7)];
        float4 b = *(const float4*)(Bw + (size_t)(n0 + lrow) * K_DIM + k0 + lk);
        sA[lrow][lk + 0] = a.x; sA[lrow][lk + 1] = a.y;
        sA[lrow][lk + 2] = a.z; sA[lrow][lk + 3] = a.w;
        sB[lrow][lk + 0] = b.x * s; sB[lrow][lk + 1] = b.y * s;
        sB[lrow][lk + 2] = b.z * s; sB[lrow][lk + 3] = b.w * s;
        __syncthreads();
#pragma unroll
        for (int kk = 0; kk < 16; ++kk) {
            float av[4], bv[4];
#pragma unroll
            for (int i = 0; i < 4; ++i) av[i] = sA[ty * 4 + i][kk];
#pragma unroll
            for (int j = 0; j < 4; ++j) bv[j] = sB[tx * 4 + j][kk];
#pragma unroll
            for (int i = 0; i < 4; ++i)
#pragma unroll
                for (int j = 0; j < 4; ++j) acc[i][j] += av[i] * bv[j];
        }
        __syncthreads();
    }
#pragma unroll
    for (int i = 0; i < 4; ++i)
#pragma unroll
        for (int j = 0; j < 4; ++j)
            C[(size_t)(m0 + ty * 4 + i) * N_DIM + n0 + tx * 4 + j] = acc[i][j];
}

// ---------------------------------------------------------------------------
extern "C" void kernel_launch(void* const* d_in, const int* in_sizes, int n_in,
                              void* d_out, int out_size, void* d_ws, size_t ws_size,
                              hipStream_t stream) {
    const float* x     = (const float*)d_in[0];
    const float* w     = (const float*)d_in[1];
    const float* scale = (const float*)d_in[2];
    float* out = (float*)d_out;

    const size_t wb_bytes = (size_t)N_DIM * K_DIM * 2;   // 264 MB
    const size_t xb_bytes = (size_t)M_DIM * K_DIM * 2;   //  59 MB
    if (ws_size >= wb_bytes + xb_bytes) {
        u16* wb = (u16*)d_ws;
        u16* xb = (u16*)((char*)d_ws + wb_bytes);
        dequant_w_kernel<<<dim3((size_t)N_DIM * K_DIM / 8 / 256), dim3(256), 0, stream>>>(
            w, scale, (ushortx8*)wb);
        cvt_x_kernel<<<dim3((size_t)M_DIM * K_DIM / 8 / 256), dim3(256), 0, stream>>>(
            x, (ushortx8*)xb);
        gemm_bf16_8ph<<<dim3(NBLK), dim3(512), 0, stream>>>(xb, wb, out);
    } else {
        fallback_gemm<<<dim3(N_DIM / 64, M_DIM / 64), dim3(256), 0, stream>>>(
            x, w, scale, out);
    }
}